// Round 9
// baseline (392.242 us; speedup 1.0000x reference)
//
#include <hip/hip_runtime.h>
#include <hip/hip_fp16.h>
#include <math.h>

#define PI_F 3.14159265358979f

typedef __attribute__((ext_vector_type(8))) __bf16 bf16x8;
typedef __attribute__((ext_vector_type(4))) float f32x4;

__device__ __forceinline__ unsigned short f2bf_rne(float v) {
  union { float f; unsigned u; } c; c.f = v;
  unsigned u = c.u;
  return (unsigned short)((u + 0x7fffu + ((u >> 16) & 1u)) >> 16);
}
__device__ __forceinline__ float bfbits2f(unsigned short b) {
  union { unsigned u; float f; } c; c.u = ((unsigned)b) << 16; return c.f;
}
__device__ __forceinline__ unsigned pk2(float a, float b) {
  return (unsigned)f2bf_rne(a) | ((unsigned)f2bf_rne(b) << 16);
}

// ===== weight pre-split + pack =====
__global__ void prep_w(const float* __restrict__ w, unsigned short* __restrict__ wpk) {
  int i = blockIdx.x * 256 + threadIdx.x;
  if (i >= 9 * 192 * 96) return;
  int pos = i / (192 * 96);
  int rem = i - pos * (192 * 96);
  int oc = rem / 96, ic = rem - oc * 96;
  float v = w[(size_t)rem * 9 + pos];
  unsigned short h = f2bf_rne(v);
  unsigned short l = f2bf_rne(v - bfbits2f(h));
  int q = ic >> 3, j = ic & 7;
  size_t base = ((size_t)(pos * 192 + oc) * 12 + q) * 16;
  wpk[base + j] = h;
  wpk[base + 8 + j] = l;
}

// ============ conv 3x3 implicit GEMM (R8 winner: T14 async-STAGE, H=2, 3 phases) ======
#define ICP 40

__global__ __launch_bounds__(256)
void conv_mfma(const float* __restrict__ x, const unsigned short* __restrict__ wpk,
               float* __restrict__ y) {
  __shared__ unsigned short patch[4 * 66 * ICP];
  const int tid  = threadIdx.x;
  const int wave = tid >> 6, lane = tid & 63;
  const int col  = lane & 15, quad = lane >> 4;
  const int w0 = blockIdx.x * 64;
  const int h0 = blockIdx.y * 2;
  const int b  = blockIdx.z;
  const float* xb = x + (size_t)b * 96 * 128 * 128;

  f32x4 acc[2][3][4];
#pragma unroll
  for (int hh = 0; hh < 2; ++hh)
#pragma unroll
    for (int mt = 0; mt < 3; ++mt)
#pragma unroll
      for (int nt = 0; nt < 4; ++nt) acc[hh][mt][nt] = (f32x4)0.f;

  const int wbase = (48 * wave + col) * 192 + quad * 16;
  const int cg = tid & 15, pg = tid >> 4;
  const int hside = tid & 1, hrr = (tid >> 1) & 3, hicl = tid >> 3;
  const int hgr = h0 - 1 + hrr;
  const int hgc = hside ? (w0 + 64) : (w0 - 1);

  float4 sv0[2], sv1[2];
  float hv;
  auto ISSUE = [&](int phase) {
    const int ic0 = phase * 32;
#pragma unroll
    for (int it = 0; it < 2; ++it) {
      int pairid = it * 16 + pg;
      int r   = pairid & 3;
      int icl = (pairid >> 2) * 2;
      int gr  = h0 - 1 + r;
      const float* r0p = xb + (size_t)(ic0 + icl) * 16384 + gr * 128 + w0 + 4 * cg;
      sv0[it] = make_float4(0.f, 0.f, 0.f, 0.f);
      sv1[it] = sv0[it];
      if ((unsigned)gr < 128u) {
        sv0[it] = *(const float4*)(r0p);
        sv1[it] = *(const float4*)(r0p + 16384);
      }
    }
    hv = 0.f;
    if ((unsigned)hgr < 128u && (unsigned)hgc < 128u)
      hv = xb[(size_t)(ic0 + hicl) * 16384 + hgr * 128 + hgc];
  };
  float4 tv0[2], tv1[2];
  auto ISSUE2 = [&](int phase) {
    const int ic0 = phase * 32;
#pragma unroll
    for (int it = 0; it < 2; ++it) {
      int pairid = 32 + it * 16 + pg;
      int r   = pairid & 3;
      int icl = (pairid >> 2) * 2;
      int gr  = h0 - 1 + r;
      const float* r0p = xb + (size_t)(ic0 + icl) * 16384 + gr * 128 + w0 + 4 * cg;
      tv0[it] = make_float4(0.f, 0.f, 0.f, 0.f);
      tv1[it] = tv0[it];
      if ((unsigned)gr < 128u) {
        tv0[it] = *(const float4*)(r0p);
        tv1[it] = *(const float4*)(r0p + 16384);
      }
    }
  };
  auto WRITE = [&]() {
#pragma unroll
    for (int it = 0; it < 2; ++it) {
      int pairid = it * 16 + pg;
      int r   = pairid & 3;
      int icl = (pairid >> 2) * 2;
      unsigned* pb = (unsigned*)&patch[(r * 66 + 1 + 4 * cg) * ICP + icl];
      pb[0]           = pk2(sv0[it].x, sv1[it].x);
      pb[ICP / 2]     = pk2(sv0[it].y, sv1[it].y);
      pb[ICP]         = pk2(sv0[it].z, sv1[it].z);
      pb[3 * ICP / 2] = pk2(sv0[it].w, sv1[it].w);
    }
#pragma unroll
    for (int it = 0; it < 2; ++it) {
      int pairid = 32 + it * 16 + pg;
      int r   = pairid & 3;
      int icl = (pairid >> 2) * 2;
      unsigned* pb = (unsigned*)&patch[(r * 66 + 1 + 4 * cg) * ICP + icl];
      pb[0]           = pk2(tv0[it].x, tv1[it].x);
      pb[ICP / 2]     = pk2(tv0[it].y, tv1[it].y);
      pb[ICP]         = pk2(tv0[it].z, tv1[it].z);
      pb[3 * ICP / 2] = pk2(tv0[it].w, tv1[it].w);
    }
    patch[(hrr * 66 + (hside ? 65 : 0)) * ICP + hicl] = f2bf_rne(hv);
  };

  ISSUE(0); ISSUE2(0);
  WRITE();
  __syncthreads();

  for (int phase = 0; phase < 3; ++phase) {
    if (phase < 2) { ISSUE(phase + 1); ISSUE2(phase + 1); }

#pragma unroll
    for (int pos = 0; pos < 9; ++pos) {
      const int dy = pos / 3, dx = pos - 3 * dy;
      bf16x8 ah[3], al[3];
#pragma unroll
      for (int mt = 0; mt < 3; ++mt) {
        const unsigned short* wp_ =
            wpk + wbase + (((pos * 192 + mt * 16) * 12 + phase * 4) * 16);
        ah[mt] = *(const bf16x8*)(wp_);
        al[mt] = *(const bf16x8*)(wp_ + 8);
      }
#pragma unroll
      for (int hh = 0; hh < 2; ++hh) {
        bf16x8 bfrag[4];
#pragma unroll
        for (int nt = 0; nt < 4; ++nt)
          bfrag[nt] = *(const bf16x8*)&patch[((dy + hh) * 66 + nt * 16 + col + dx) * ICP + quad * 8];
#pragma unroll
        for (int mt = 0; mt < 3; ++mt)
#pragma unroll
          for (int nt = 0; nt < 4; ++nt) {
            acc[hh][mt][nt] = __builtin_amdgcn_mfma_f32_16x16x32_bf16(ah[mt], bfrag[nt], acc[hh][mt][nt], 0, 0, 0);
            acc[hh][mt][nt] = __builtin_amdgcn_mfma_f32_16x16x32_bf16(al[mt], bfrag[nt], acc[hh][mt][nt], 0, 0, 0);
          }
      }
    }

    if (phase < 2) {
      __syncthreads();
      WRITE();
      __syncthreads();
    }
  }

  float* yb = y + (size_t)b * 48 * 65536;
#pragma unroll
  for (int hh = 0; hh < 2; ++hh) {
    const int h = h0 + hh;
#pragma unroll
    for (int mt = 0; mt < 3; ++mt) {
#pragma unroll
      for (int p = 0; p < 2; ++p) {
        int r0 = 2 * p;
        int oc = 48 * wave + mt * 16 + quad * 4 + r0;
        int cq = oc >> 2, r2 = (oc >> 1) & 1;
        float* orow = yb + ((size_t)cq * 256 + 2 * h + r2) * 256;
#pragma unroll
        for (int nt = 0; nt < 4; ++nt) {
          int w = w0 + nt * 16 + col;
          *(float2*)&orow[2 * w] = make_float2(acc[hh][mt][nt][r0], acc[hh][mt][nt][r0 + 1]);
        }
      }
    }
  }
}

// ============ fallback fp32 conv ============
#define OCB 8
#define ICB 2
#define PSTRIDE 67
__global__ __launch_bounds__(256)
void conv_ps_kernel(const float* __restrict__ x, const float* __restrict__ wgt,
                    float* __restrict__ y) {
  __shared__ float wsh[OCB * 96 * 9];
  __shared__ float patch[ICB * 18 * PSTRIDE];
  const int tid = threadIdx.x;
  const int b = blockIdx.z / 24, ocg = blockIdx.z % 24;
  const int row0 = blockIdx.y * 16, col0 = blockIdx.x * 64;
  const int tx = tid & 15, ty = tid >> 4;
  for (int i = tid; i < OCB * 96 * 9; i += 256) wsh[i] = wgt[ocg * (OCB * 96 * 9) + i];
  float acc[OCB][4];
#pragma unroll
  for (int o = 0; o < OCB; ++o)
#pragma unroll
    for (int p = 0; p < 4; ++p) acc[o][p] = 0.f;
  const float* xb = x + (size_t)b * 96 * 128 * 128;
  for (int ic0 = 0; ic0 < 96; ic0 += ICB) {
    __syncthreads();
    for (int idx = tid; idx < ICB * 18 * 66; idx += 256) {
      int j = idx / (18 * 66), rem = idx - j * (18 * 66);
      int r = rem / 66, c = rem - r * 66;
      int gr = row0 - 1 + r, gc = col0 - 1 + c;
      float v = 0.f;
      if ((unsigned)gr < 128u && (unsigned)gc < 128u)
        v = xb[((size_t)(ic0 + j) * 128 + gr) * 128 + gc];
      patch[j * (18 * PSTRIDE) + r * PSTRIDE + c] = v;
    }
    __syncthreads();
#pragma unroll
    for (int j = 0; j < ICB; ++j) {
      float xr[3][6];
      const float* pp = &patch[j * (18 * PSTRIDE) + ty * PSTRIDE + tx * 4];
#pragma unroll
      for (int dy = 0; dy < 3; ++dy)
#pragma unroll
        for (int dx = 0; dx < 6; ++dx) xr[dy][dx] = pp[dy * PSTRIDE + dx];
#pragma unroll
      for (int o = 0; o < OCB; ++o) {
        const float* wp = &wsh[(o * 96 + ic0 + j) * 9];
#pragma unroll
        for (int p = 0; p < 4; ++p)
          acc[o][p] += wp[0] * xr[0][p] + wp[1] * xr[0][p + 1] + wp[2] * xr[0][p + 2]
                     + wp[3] * xr[1][p] + wp[4] * xr[1][p + 1] + wp[5] * xr[1][p + 2]
                     + wp[6] * xr[2][p] + wp[7] * xr[2][p + 1] + wp[8] * xr[2][p + 2];
      }
    }
  }
  const int h = row0 + ty;
#pragma unroll
  for (int o = 0; o < OCB; ++o) {
    int ocglob = ocg * OCB + o;
    int cq = ocglob >> 2, r2 = (ocglob >> 1) & 1, s2 = ocglob & 1;
    float* orow = y + (((size_t)b * 48 + cq) * 256 + (2 * h + r2)) * 256;
#pragma unroll
    for (int p = 0; p < 4; ++p) orow[2 * (col0 + tx * 4 + p) + s2] = acc[o][p];
  }
}

// ================= wave-synchronous register radix-4 FFT (256 = 4^4) =================
// Packed 2-real-lines filtering. Per-dim mask M keeps k in {0..63}U{192..255}.
// M = S - P64 where S (keep +-64, symmetric) has a REAL kernel: S-filtered real
// data is real. Pack two real lines z=a+ib, run the M-transform G once; then
// G_S(z) = G(z) + Z(64)*i^n, whose Re/Im are the two S-filtered lines. The M-vs-S
// difference is a rank-1 per-line correction c*i^n with c = -A(64)/256 captured
// via a wave reduction of the input. Cross-term handled by one aux filter/image.
__device__ __forceinline__ float2 cadd(float2 a, float2 b){return make_float2(a.x+b.x, a.y+b.y);}
__device__ __forceinline__ float2 csub(float2 a, float2 b){return make_float2(a.x-b.x, a.y-b.y);}
__device__ __forceinline__ float2 cmul(float2 a, float2 b){return make_float2(a.x*b.x-a.y*b.y, a.x*b.y+a.y*b.x);}
__device__ __forceinline__ float2 cmulc(float2 a, float2 b){return make_float2(a.x*b.x+a.y*b.y, a.y*b.x-a.x*b.y);}

__device__ __forceinline__ float2 ipow(int m) {   // i^m
  m &= 3;
  float2 v;
  v.x = (m == 0) ? 1.f : ((m == 2) ? -1.f : 0.f);
  v.y = (m == 1) ? 1.f : ((m == 3) ? -1.f : 0.f);
  return v;
}
__device__ __forceinline__ float2 wave_sum(float2 v) {
#pragma unroll
  for (int off = 32; off; off >>= 1) {
    v.x += __shfl_xor(v.x, off);
    v.y += __shfl_xor(v.y, off);
  }
  return v;
}

__device__ __forceinline__ void dft4(float2 r[4]) {
  float2 e0 = cadd(r[0], r[2]), e1 = csub(r[0], r[2]);
  float2 o0 = cadd(r[1], r[3]), o1 = csub(r[1], r[3]);
  r[0] = cadd(e0, o0);
  r[2] = csub(e0, o0);
  r[1] = make_float2(e1.x + o1.y, e1.y - o1.x);
  r[3] = make_float2(e1.x - o1.y, e1.y + o1.x);
}
__device__ __forceinline__ void idft4(float2 r[4]) {
  float2 e0 = cadd(r[0], r[2]), e1 = csub(r[0], r[2]);
  float2 o0 = cadd(r[1], r[3]), o1 = csub(r[1], r[3]);
  r[0] = cadd(e0, o0);
  r[2] = csub(e0, o0);
  r[1] = make_float2(e1.x - o1.y, e1.y + o1.x);
  r[3] = make_float2(e1.x + o1.y, e1.y - o1.x);
}

struct TwSet {
  float2 f1[3], f2[3], f3[3], i2[4], i3[4];
};

__device__ __forceinline__ void load_tw(TwSet& T, const float2* __restrict__ tw, int l) {
  const int qq = l >> 4, m = l & 15, q2r = (l >> 2) & 3, c2 = l & 3;
  T.f1[0] = tw[l];
  T.f1[1] = tw[(2 * l) & 255];
  T.f1[2] = tw[(3 * l) & 255];
  T.f2[0] = tw[(4 * m) & 255];
  T.f2[1] = tw[(8 * m) & 255];
  T.f2[2] = tw[(12 * m) & 255];
  T.f3[0] = tw[(16 * c2) & 255];
  T.f3[1] = tw[(32 * c2) & 255];
  T.f3[2] = tw[(48 * c2) & 255];
  T.i2[0] = tw[(4 * c2 * q2r) & 255];
  T.i2[1] = tw[(4 * (c2 + 4) * q2r) & 255];
  T.i2[2] = tw[(4 * (c2 + 8) * q2r) & 255];
  T.i2[3] = tw[(4 * (c2 + 12) * q2r) & 255];
  T.i3[0] = tw[(m * qq) & 255];
  T.i3[1] = tw[((m + 16) * qq) & 255];
  T.i3[2] = tw[((m + 32) * qq) & 255];
  T.i3[3] = tw[((m + 48) * qq) & 255];
}

// r[t] in: x[l + 64t]; out: (M-filtered x)[l + 64t] (unnormalized).
template <int ST>
__device__ void fft_line_masked(float2 r[4], float2* __restrict__ S, const TwSet& T, int l) {
  const int qq = l >> 4, m = l & 15;
  const int g = l >> 2, q2r = (l >> 2) & 3, c2 = l & 3;
  dft4(r);
  r[1] = cmul(r[1], T.f1[0]);
  r[2] = cmul(r[2], T.f1[1]);
  r[3] = cmul(r[3], T.f1[2]);
  S[ST * l] = r[0];
  S[ST * (64 + l)] = r[1];
  S[ST * (128 + l)] = r[2];
  S[ST * (192 + l)] = r[3];
#pragma unroll
  for (int t = 0; t < 4; ++t) r[t] = S[ST * (qq * 64 + m + 16 * t)];
  dft4(r);
  r[1] = cmul(r[1], T.f2[0]);
  r[2] = cmul(r[2], T.f2[1]);
  r[3] = cmul(r[3], T.f2[2]);
#pragma unroll
  for (int q2 = 0; q2 < 4; ++q2) S[ST * (qq * 64 + q2 * 16 + ((m + 4 * q2) & 15))] = r[q2];
#pragma unroll
  for (int t = 0; t < 4; ++t) r[t] = S[ST * (qq * 64 + q2r * 16 + ((c2 + 4 * t + 4 * q2r) & 15))];
  dft4(r);
  r[1] = cmul(r[1], T.f3[0]);
  r[2] = cmul(r[2], T.f3[1]);
  r[3] = cmul(r[3], T.f3[2]);
#pragma unroll
  for (int q3 = 0; q3 < 4; ++q3) S[ST * (g * 16 + ((4 * q3 + c2 + g) & 15))] = r[q3];
#pragma unroll
  for (int t = 0; t < 4; ++t) r[t] = S[ST * (g * 16 + ((4 * c2 + t + g) & 15))];
  dft4(r);
  {
    float2 V0 = r[0], V3 = r[3];
    r[0] = cadd(V0, V3);
    r[1] = make_float2(V0.x + V3.y, V0.y - V3.x);
    r[2] = csub(V0, V3);
    r[3] = make_float2(V0.x - V3.y, V0.y + V3.x);
  }
  r[1] = cmulc(r[1], T.f3[0]);
  r[2] = cmulc(r[2], T.f3[1]);
  r[3] = cmulc(r[3], T.f3[2]);
#pragma unroll
  for (int j = 0; j < 4; ++j) S[ST * (g * 16 + ((4 * c2 + j + g) & 15))] = r[j];
#pragma unroll
  for (int t = 0; t < 4; ++t) r[t] = S[ST * (g * 16 + ((4 * t + c2 + g) & 15))];
  idft4(r);
  r[0] = cmulc(r[0], T.i2[0]);
  r[1] = cmulc(r[1], T.i2[1]);
  r[2] = cmulc(r[2], T.i2[2]);
  r[3] = cmulc(r[3], T.i2[3]);
#pragma unroll
  for (int t1 = 0; t1 < 4; ++t1) S[ST * (qq * 64 + q2r * 16 + ((c2 + 4 * t1 + 4 * q2r) & 15))] = r[t1];
#pragma unroll
  for (int t = 0; t < 4; ++t) r[t] = S[ST * (qq * 64 + t * 16 + ((m + 4 * t) & 15))];
  idft4(r);
  r[0] = cmulc(r[0], T.i3[0]);
  r[1] = cmulc(r[1], T.i3[1]);
  r[2] = cmulc(r[2], T.i3[2]);
  r[3] = cmulc(r[3], T.i3[3]);
#pragma unroll
  for (int t2 = 0; t2 < 4; ++t2) S[ST * (qq * 64 + m + 16 * t2)] = r[t2];
#pragma unroll
  for (int t = 0; t < 4; ++t) r[t] = S[ST * (t * 64 + l)];
  idft4(r);
}

// Row pass: packed pairs — 8 rows/block (2 per wave). Outputs real fp16 z1 + c scalars.
__global__ __launch_bounds__(256)
void fft_rows_kernel(const float* __restrict__ y, __half* __restrict__ z1,
                     float2* __restrict__ cvec) {
  __shared__ float2 S[4 * 256];
  __shared__ float2 tw[256];
  const int tid = threadIdx.x;
  {
    float sn, cs;
    __sincosf(-2.f * PI_F * (float)tid / 256.f, &sn, &cs);
    tw[tid] = make_float2(cs, sn);
  }
  __syncthreads();
  const int wv = tid >> 6, l = tid & 63;
  TwSet T;
  load_tw(T, tw, l);
  const int pair = blockIdx.x * 4 + wv;        // rows 2*pair, 2*pair+1 within chunk
  const size_t abase = (size_t)pair * 512;
  float2 r[4];
#pragma unroll
  for (int t = 0; t < 4; ++t)
    r[t] = make_float2(y[abase + l + 64 * t], y[abase + 256 + l + 64 * t]);
  // bin 64 / bin 192 of the packed input (wave reduction)
  float2 s = cadd(cadd(r[0], r[1]), cadd(r[2], r[3]));
  float2 Z64  = wave_sum(cmul(s, tw[(64 * l) & 255]));
  float2 Z192 = wave_sum(cmul(s, tw[(192 * l) & 255]));
  fft_line_masked<1>(r, S + wv * 256, T, l);
  const float2 u = ipow(l);                    // i^n, n&3 == l&3
  const float2 zu = cmul(Z64, u);
#pragma unroll
  for (int t = 0; t < 4; ++t) {
    float2 gS = cadd(r[t], zu);                // G_S(z): Re = S-filt row a, Im = row b
    z1[abase + l + 64 * t]       = __float2half_rn(gS.x * (1.f / 256.f));
    z1[abase + 256 + l + 64 * t] = __float2half_rn(gS.y * (1.f / 256.f));
  }
  if (l == 0) {
    float2 cj = make_float2(Z192.x, -Z192.y);
    float2 A = make_float2(0.5f * (Z64.x + cj.x), 0.5f * (Z64.y + cj.y));  // bin64 of a
    float2 q = make_float2(Z64.x - cj.x, Z64.y - cj.y);
    float2 B = make_float2(0.5f * q.y, -0.5f * q.x);                       // bin64 of b
    cvec[2 * pair]     = make_float2(-A.x * (1.f / 256.f), -A.y * (1.f / 256.f));
    cvec[2 * pair + 1] = make_float2(-B.x * (1.f / 256.f), -B.y * (1.f / 256.f));
  }
}

// Aux: M-filter the per-row scalar vector c (one 256-pt line per image)
__global__ __launch_bounds__(256)
void fft_aux_kernel(const float2* __restrict__ cvec, float2* __restrict__ Mc, int nimg) {
  __shared__ float2 S[4 * 256];
  __shared__ float2 tw[256];
  const int tid = threadIdx.x;
  {
    float sn, cs;
    __sincosf(-2.f * PI_F * (float)tid / 256.f, &sn, &cs);
    tw[tid] = make_float2(cs, sn);
  }
  __syncthreads();
  const int wv = tid >> 6, l = tid & 63;
  const int img = blockIdx.x * 4 + wv;
  TwSet T;
  load_tw(T, tw, l);
  if (img >= nimg) return;
  float2 r[4];
#pragma unroll
  for (int t = 0; t < 4; ++t) r[t] = cvec[(size_t)img * 256 + l + 64 * t];
  fft_line_masked<1>(r, S + wv * 256, T, l);
#pragma unroll
  for (int t = 0; t < 4; ++t) Mc[(size_t)img * 256 + l + 64 * t] = r[t];
}

// Col pass: 16-col strip (real floats), packed column pairs, rank-1 corrections,
// magnitude + blend.
#define CSTF 17
__global__ __launch_bounds__(256)
void fft_cols_kernel(const __half* __restrict__ z1, const float2* __restrict__ Mc,
                     const float* __restrict__ yy, float* __restrict__ out,
                     const float* __restrict__ betaPtr) {
  __shared__ float strip[256 * CSTF];
  __shared__ float2 S2[4 * 256];
  __shared__ float2 tw[256];
  __shared__ float2 McS[256];
  const int tid = threadIdx.x;
  {
    float sn, cs;
    __sincosf(-2.f * PI_F * (float)tid / 256.f, &sn, &cs);
    tw[tid] = make_float2(cs, sn);
  }
  const int img = blockIdx.x >> 4;
  const int c0 = (blockIdx.x & 15) * 16;
  const size_t ibase = (size_t)img * 65536;
  McS[tid] = Mc[(size_t)img * 256 + tid];
#pragma unroll
  for (int it = 0; it < 16; ++it) {
    int idx = it * 256 + tid;
    int rrow = idx >> 4, cc = idx & 15;
    strip[rrow * CSTF + cc] = __half2float(z1[ibase + (size_t)rrow * 256 + c0 + cc]);
  }
  __syncthreads();
  const int wv = tid >> 6, l = tid & 63;
  TwSet T;
  load_tw(T, tw, l);
  const float2 u = ipow(l);                    // i^h, h&3 == l&3
  float2 r[4];
#pragma unroll
  for (int p = 0; p < 2; ++p) {
    const int cc = wv * 4 + p * 2;             // local col (even)
    const int wglob = c0 + cc;
#pragma unroll
    for (int t = 0; t < 4; ++t) {
      const float* sp = &strip[(l + 64 * t) * CSTF + cc];
      r[t] = make_float2(sp[0], sp[1]);        // packed: col cc + i*col cc+1
    }
    float2 s = cadd(cadd(r[0], r[1]), cadd(r[2], r[3]));
    float2 Z64  = wave_sum(cmul(s, tw[(64 * l) & 255]));
    float2 Z192 = wave_sum(cmul(s, tw[(192 * l) & 255]));
    fft_line_masked<1>(r, S2 + wv * 256, T, l);
    float2 cj = make_float2(Z192.x, -Z192.y);
    float2 A = make_float2(0.5f * (Z64.x + cj.x), 0.5f * (Z64.y + cj.y));
    float2 q = make_float2(Z64.x - cj.x, Z64.y - cj.y);
    float2 B = make_float2(0.5f * q.y, -0.5f * q.x);
    const float2 zu = cmul(Z64, u);
    const float2 Au = cmul(A, u);
    const float2 Bu = cmul(B, u);
    const float2 iw  = ipow(wglob);
    const float2 iw1 = ipow(wglob + 1);
#pragma unroll
    for (int t = 0; t < 4; ++t) {
      int h = l + 64 * t;
      float2 gS = cadd(r[t], zu);              // Re = S-filt col cc, Im = col cc+1
      float2 mc  = cmul(McS[h], iw);
      float2 mc1 = cmul(McS[h], iw1);
      float2 Fc  = make_float2(gS.x - Au.x + mc.x,  -Au.y + mc.y);
      float2 Fc1 = make_float2(gS.y - Bu.x + mc1.x, -Bu.y + mc1.y);
      strip[h * CSTF + cc]     = sqrtf(Fc.x * Fc.x + Fc.y * Fc.y) * (1.f / 256.f);
      strip[h * CSTF + cc + 1] = sqrtf(Fc1.x * Fc1.x + Fc1.y * Fc1.y) * (1.f / 256.f);
    }
  }
  __syncthreads();
  const float beta = betaPtr[0];
  const float a1 = 1.f - 2.f * beta;
#pragma unroll
  for (int it = 0; it < 16; ++it) {
    int idx = it * 256 + tid;
    int rrow = idx >> 4, cc = idx & 15;
    size_t gi = ibase + (size_t)rrow * 256 + c0 + cc;
    out[gi] = beta * yy[gi] + a1 * strip[rrow * CSTF + cc];
  }
}

// ================= launch =================
extern "C" void kernel_launch(void* const* d_in, const int* in_sizes, int n_in,
                              void* d_out, int out_size, void* d_ws, size_t ws_size,
                              hipStream_t stream) {
  const float* x = (const float*)d_in[0];
  const float* wgt = (const float*)d_in[1];
  const float* beta = (const float*)d_in[2];
  float* out = (float*)d_out;

  const size_t wplane = (size_t)9 * 192 * 96;
  const size_t wbytes = (2 * wplane * sizeof(unsigned short) + 255) & ~(size_t)255;
  // per image: z1 real fp16 (128KB) + c (2KB) + Mc (2KB)
  const size_t per_img = 65536ull * 2 + 256 * 8 + 256 * 8;
  const int NIMG = 8 * 48;

  char* fftws;
  size_t fft_bytes;

  if (ws_size >= wbytes + per_img) {
    unsigned short* wpk = (unsigned short*)d_ws;
    fftws = (char*)d_ws + wbytes;
    fft_bytes = ws_size - wbytes;
    prep_w<<<648, 256, 0, stream>>>(wgt, wpk);
    conv_mfma<<<dim3(2, 64, 8), 256, 0, stream>>>(x, wpk, out);
  } else {
    fftws = (char*)d_ws;
    fft_bytes = ws_size;
    conv_ps_kernel<<<dim3(2, 8, 192), 256, 0, stream>>>(x, wgt, out);
  }

  int chunk = (int)(fft_bytes / per_img);
  if (chunk < 1) chunk = 1;
  if (chunk > NIMG) chunk = NIMG;
  __half* z1h = (__half*)fftws;
  float2* cvec = (float2*)(fftws + (size_t)chunk * 131072);
  float2* Mc = cvec + (size_t)chunk * 256;

  for (int img0 = 0; img0 < NIMG; img0 += chunk) {
    int n = NIMG - img0;
    if (n > chunk) n = chunk;
    float* ych = out + (size_t)img0 * 65536;
    fft_rows_kernel<<<n * 32, 256, 0, stream>>>(ych, z1h, cvec);
    fft_aux_kernel<<<(n + 3) / 4, 256, 0, stream>>>(cvec, Mc, n);
    fft_cols_kernel<<<n * 16, 256, 0, stream>>>(z1h, Mc, ych, ych, beta);
  }
}